// Round 1
// baseline (469.597 us; speedup 1.0000x reference)
//
#include <hip/hip_runtime.h>
#include <hip/hip_bf16.h>

#define BATCH     1024
#define INPUT_DIM 20000
#define UNITS     4096
#define NNZ       800000

// ---------------- ws layout (bytes, all 256-aligned) ----------------
// xT bf16 [INPUT_DIM][BATCH]          : 20000*1024*2 = 40,960,000
// outT f32 [UNITS][BATCH]             :  4096*1024*4 = 16,777,216
// counts  [UNITS]                     :  16,384
// offsets [UNITS]                     :  16,384
// cursor  [UNITS]                     :  16,384
// packed int2 [NNZ]                   :  6,400,000
#define WS_XT      0
#define WS_OUTT    40960000
#define WS_COUNTS  (WS_OUTT + 16777216)
#define WS_OFFSETS (WS_COUNTS + 16384)
#define WS_CURSOR  (WS_OFFSETS + 16384)
#define WS_PACKED  (WS_CURSOR + 16384)

// -------- 1. transpose + convert: x[B][D] f32 -> xT[D][B] bf16 --------
__global__ void transpose_in_kernel(const float* __restrict__ x,
                                    unsigned short* __restrict__ xT) {
    __shared__ float tile[32][33];
    int d0 = blockIdx.x * 32;   // input-dim tile (625 tiles, exact)
    int b0 = blockIdx.y * 32;   // batch tile (32 tiles, exact)
    int tx = threadIdx.x, ty = threadIdx.y;
#pragma unroll
    for (int i = 0; i < 32; i += 8)
        tile[ty + i][tx] = x[(size_t)(b0 + ty + i) * INPUT_DIM + d0 + tx];
    __syncthreads();
#pragma unroll
    for (int i = 0; i < 32; i += 8) {
        __hip_bfloat16 h = __float2bfloat16(tile[tx][ty + i]);
        xT[(size_t)(d0 + ty + i) * BATCH + b0 + tx] = *(unsigned short*)&h;
    }
}

// -------- 2. zero the histogram --------
__global__ void zero_kernel(int* __restrict__ p, int n) {
    int i = blockIdx.x * blockDim.x + threadIdx.x;
    if (i < n) p[i] = 0;
}

// -------- 3. histogram of columns --------
__global__ void hist_kernel(const int* __restrict__ ind, int* __restrict__ cnt) {
    int i = blockIdx.x * blockDim.x + threadIdx.x;
    if (i < NNZ) atomicAdd(&cnt[ind[2 * i + 1]], 1);
}

// -------- 4. exclusive scan over 4096 counts (single block of 1024) --------
__global__ void scan_kernel(const int* __restrict__ cnt, int* __restrict__ offs,
                            int* __restrict__ cursor) {
    __shared__ int sums[1024];
    int t = threadIdx.x;
    int c0 = cnt[4 * t], c1 = cnt[4 * t + 1], c2 = cnt[4 * t + 2], c3 = cnt[4 * t + 3];
    int local = c0 + c1 + c2 + c3;
    sums[t] = local;
    __syncthreads();
    for (int o = 1; o < 1024; o <<= 1) {
        int v = (t >= o) ? sums[t - o] : 0;
        __syncthreads();
        sums[t] += v;
        __syncthreads();
    }
    int base = sums[t] - local;  // exclusive prefix
    int o0 = base, o1 = base + c0, o2 = o1 + c1, o3 = o2 + c2;
    offs[4 * t] = o0; offs[4 * t + 1] = o1; offs[4 * t + 2] = o2; offs[4 * t + 3] = o3;
    cursor[4 * t] = o0; cursor[4 * t + 1] = o1; cursor[4 * t + 2] = o2; cursor[4 * t + 3] = o3;
}

// -------- 5. scatter nnz into CSC order: packed[pos] = {row, val_bits} --------
__global__ void scatter_kernel(const int* __restrict__ ind, const float* __restrict__ vals,
                               int* __restrict__ cursor, int2* __restrict__ packed) {
    int i = blockIdx.x * blockDim.x + threadIdx.x;
    if (i < NNZ) {
        int r = ind[2 * i];
        int c = ind[2 * i + 1];
        int pos = atomicAdd(&cursor[c], 1);
        packed[pos] = make_int2(r, __float_as_int(vals[i]));
    }
}

// -------- 6. spmm: block = one output column; thread = 4 batch elems --------
__device__ __forceinline__ void acc4(uint2 q, float v,
                                     float& a0, float& a1, float& a2, float& a3) {
    a0 = fmaf(v, __uint_as_float(q.x << 16), a0);
    a1 = fmaf(v, __uint_as_float(q.x & 0xFFFF0000u), a1);
    a2 = fmaf(v, __uint_as_float(q.y << 16), a2);
    a3 = fmaf(v, __uint_as_float(q.y & 0xFFFF0000u), a3);
}

__global__ __launch_bounds__(256) void spmm_kernel(
    const int2* __restrict__ packed, const int* __restrict__ offs,
    const int* __restrict__ cnt, const unsigned short* __restrict__ xT,
    float* __restrict__ outT) {
    int u = blockIdx.x;
    int t = threadIdx.x;
    int start = offs[u];
    int n = cnt[u];
    int b = t * 4;
    float a0 = 0.f, a1 = 0.f, a2 = 0.f, a3 = 0.f;

    int j = 0;
    for (; j + 4 <= n; j += 4) {
        int2 p0 = packed[start + j + 0];
        int2 p1 = packed[start + j + 1];
        int2 p2 = packed[start + j + 2];
        int2 p3 = packed[start + j + 3];
        // 4 independent 8B gathers in flight
        uint2 q0 = *(const uint2*)(xT + (size_t)p0.x * BATCH + b);
        uint2 q1 = *(const uint2*)(xT + (size_t)p1.x * BATCH + b);
        uint2 q2 = *(const uint2*)(xT + (size_t)p2.x * BATCH + b);
        uint2 q3 = *(const uint2*)(xT + (size_t)p3.x * BATCH + b);
        acc4(q0, __int_as_float(p0.y), a0, a1, a2, a3);
        acc4(q1, __int_as_float(p1.y), a0, a1, a2, a3);
        acc4(q2, __int_as_float(p2.y), a0, a1, a2, a3);
        acc4(q3, __int_as_float(p3.y), a0, a1, a2, a3);
    }
    for (; j < n; j++) {
        int2 p = packed[start + j];
        uint2 q = *(const uint2*)(xT + (size_t)p.x * BATCH + b);
        acc4(q, __int_as_float(p.y), a0, a1, a2, a3);
    }

    float* op = outT + (size_t)u * BATCH + b;
    op[0] = a0; op[1] = a1; op[2] = a2; op[3] = a3;
}

// -------- 7. transpose outT[U][B] -> out[B][U], fused bias + tanh --------
__global__ void transpose_out_kernel(const float* __restrict__ outT,
                                     const float* __restrict__ bias,
                                     float* __restrict__ out) {
    __shared__ float tile[32][33];
    int u0 = blockIdx.x * 32;   // 128 tiles
    int b0 = blockIdx.y * 32;   // 32 tiles
    int tx = threadIdx.x, ty = threadIdx.y;
#pragma unroll
    for (int i = 0; i < 32; i += 8)
        tile[ty + i][tx] = outT[(size_t)(u0 + ty + i) * BATCH + b0 + tx];
    __syncthreads();
#pragma unroll
    for (int i = 0; i < 32; i += 8) {
        int u = u0 + tx;
        out[(size_t)(b0 + ty + i) * UNITS + u] = tanhf(tile[tx][ty + i] + bias[u]);
    }
}

extern "C" void kernel_launch(void* const* d_in, const int* in_sizes, int n_in,
                              void* d_out, int out_size, void* d_ws, size_t ws_size,
                              hipStream_t stream) {
    const float* x    = (const float*)d_in[0];  // [1024, 20000]
    const float* vals = (const float*)d_in[1];  // [800000]
    const float* bias = (const float*)d_in[2];  // [4096]
    const int*   ind  = (const int*)d_in[3];    // [800000, 2]
    float* out = (float*)d_out;                 // [1024, 4096]

    char* ws = (char*)d_ws;
    unsigned short* xT = (unsigned short*)(ws + WS_XT);
    float* outT        = (float*)(ws + WS_OUTT);
    int*   counts      = (int*)(ws + WS_COUNTS);
    int*   offsets     = (int*)(ws + WS_OFFSETS);
    int*   cursor      = (int*)(ws + WS_CURSOR);
    int2*  packed      = (int2*)(ws + WS_PACKED);

    // 1. x -> xT (bf16)
    transpose_in_kernel<<<dim3(INPUT_DIM / 32, BATCH / 32), dim3(32, 8), 0, stream>>>(x, xT);
    // 2. zero histogram
    zero_kernel<<<(UNITS + 255) / 256, 256, 0, stream>>>(counts, UNITS);
    // 3. histogram of columns
    hist_kernel<<<NNZ / 256, 256, 0, stream>>>(ind, counts);
    // 4. scan -> offsets, cursor
    scan_kernel<<<1, 1024, 0, stream>>>(counts, offsets, cursor);
    // 5. scatter into CSC
    scatter_kernel<<<NNZ / 256, 256, 0, stream>>>(ind, vals, cursor, packed);
    // 6. sparse matmul: outT[u][b]
    spmm_kernel<<<UNITS, 256, 0, stream>>>(packed, offsets, counts, xT, outT);
    // 7. outT -> out with bias + tanh
    transpose_out_kernel<<<dim3(UNITS / 32, BATCH / 32), dim3(32, 8), 0, stream>>>(outT, bias, out);
}